// Round 13
// baseline (221.856 us; speedup 1.0000x reference)
//
#include <hip/hip_runtime.h>
#include <hip/hip_fp16.h>
#include <cstdint>
#include <cstddef>

#define NPTS 8192
#define DDIM 128
#define BATCH 2
#define NROWS (BATCH * NPTS)
#define EPSGAP 1.0f   // certified: RTZ f16 dist err <= ~0.5 < 1.0 (Cauchy-Schwarz)
#define NCOLT 64      // 8192 / 128 column tiles (partials per row)
#define WCAP 512      // per-wave candidate capacity in finalize phase 2

typedef __attribute__((ext_vector_type(8))) _Float16 half8v;
typedef __attribute__((ext_vector_type(4))) float f32x4;

typedef __attribute__((address_space(3))) unsigned int as3_uint;
typedef const __attribute__((address_space(1))) unsigned int as1_uint;

// pack 8 fp32 -> 8 f16 (RTZ) via v_cvt_pkrtz; bit-assemble into half8v
static __device__ __forceinline__ half8v cvt8(f32x4 lo, f32x4 hi) {
    union { unsigned int u[4]; half8v h; } cv;
    cv.u[0] = __builtin_bit_cast(unsigned int, __builtin_amdgcn_cvt_pkrtz(lo.x, lo.y));
    cv.u[1] = __builtin_bit_cast(unsigned int, __builtin_amdgcn_cvt_pkrtz(lo.z, lo.w));
    cv.u[2] = __builtin_bit_cast(unsigned int, __builtin_amdgcn_cvt_pkrtz(hi.x, hi.y));
    cv.u[3] = __builtin_bit_cast(unsigned int, __builtin_amdgcn_cvt_pkrtz(hi.z, hi.w));
    return cv.h;
}

// ---- MFMA GEMM, fp32-direct staging (NO split kernel) -------------------------
// Stages fp32 via global_load_lds (async; R9's failure was sync reg-staging),
// converts to f16 at LDS-read with v_cvt_pkrtz. K in 4 phases of 32 keeps LDS
// at ~35 KB -> same blocks/CU as R11. y2 computed in-kernel from the pre-cvt
// fp32 B registers. 512 MB output zeroing stays here (drain fully hidden -
// validated R10/R11). XCD chunking 32x32: 2MB A + 2MB B = 4MB = L2.
__global__ __launch_bounds__(256) void gemm_mfma(
    const float* __restrict__ f0, const float* __restrict__ f1,
    float* __restrict__ pv1, float* __restrict__ pv2, unsigned int* __restrict__ pidx,
    float* __restrict__ outZero)
{
    __shared__ __align__(16) float As[128 * 32];
    __shared__ __align__(16) float Bs[128 * 32];
    __shared__ float rv1[2][128];
    __shared__ float rv2[2][128];
    __shared__ unsigned int ri[2][128];
    __shared__ float y2s[128];

    const unsigned flat = blockIdx.x;          // 0..8191
    const unsigned xcd  = flat & 7u;
    const unsigned q    = flat >> 3;           // 0..1023
    const int b    = (int)(xcd >> 2);
    const int bm   = (int)(((xcd >> 1) & 1u) * 32 + (q & 31));
    const int bnc  = (int)((xcd & 1u) * 32 + (q >> 5));

    const int tid  = threadIdx.x;
    const int lane = tid & 63;
    const int wid  = tid >> 6;
    const int wr   = wid >> 1, wc = wid & 1;
    const int l15  = lane & 15, l4 = lane >> 4;
    const int row0 = bm * 128, col0 = bnc * 128;

    const float* Abase = f0 + ((size_t)b * NPTS + row0) * DDIM;
    const float* Bbase = f1 + ((size_t)b * NPTS + col0) * DDIM;

    f32x4 acc[4][4];
#pragma unroll
    for (int i = 0; i < 4; ++i)
#pragma unroll
        for (int j = 0; j < 4; ++j) acc[i][j] = (f32x4)0.0f;

    float y2p[4] = {0.0f, 0.0f, 0.0f, 0.0f};

#pragma unroll
    for (int ph = 0; ph < 4; ++ph) {          // K quarters: 32 cols each
        __syncthreads();                      // prev-phase LDS reads complete
        {
            const int ko = ph * 32;
#pragma unroll
            for (int it = 0; it < 4; ++it) {
                int flat2 = it * 256 + tid;   // 16B-chunk id 0..1023 (128 rows x 8 chunks)
                int r = flat2 >> 3, kc = flat2 & 7;
                int kcs = kc ^ (r & 7);       // inverse-swizzled source chunk (4 fp32)
                const float* ga = Abase + (size_t)r * DDIM + ko + kcs * 4;
                const float* gb = Bbase + (size_t)r * DDIM + ko + kcs * 4;
                __builtin_amdgcn_global_load_lds((as1_uint*)ga, (as3_uint*)&As[flat2 * 4], 16, 0, 0);
                __builtin_amdgcn_global_load_lds((as1_uint*)gb, (as3_uint*)&Bs[flat2 * 4], 16, 0, 0);
            }
        }
        __syncthreads();                      // staged data visible
        half8v a[4], bf[4];
#pragma unroll
        for (int i = 0; i < 4; ++i) {
            const int ra = wr * 64 + i * 16 + l15;
            const int c0 = (2 * l4) ^ (ra & 7);
            const int c1 = (2 * l4 + 1) ^ (ra & 7);
            const f32x4 lo = *reinterpret_cast<const f32x4*>(&As[ra * 32 + c0 * 4]);
            const f32x4 hi = *reinterpret_cast<const f32x4*>(&As[ra * 32 + c1 * 4]);
            a[i] = cvt8(lo, hi);
        }
#pragma unroll
        for (int j = 0; j < 4; ++j) {
            const int rb = wc * 64 + j * 16 + l15;
            const int c0 = (2 * l4) ^ (rb & 7);
            const int c1 = (2 * l4 + 1) ^ (rb & 7);
            const f32x4 lo = *reinterpret_cast<const f32x4*>(&Bs[rb * 32 + c0 * 4]);
            const f32x4 hi = *reinterpret_cast<const f32x4*>(&Bs[rb * 32 + c1 * 4]);
            // y2 partial from exact fp32 (before conversion) - free VALU work
            y2p[j] = fmaf(lo.x, lo.x, fmaf(lo.y, lo.y, fmaf(lo.z, lo.z, fmaf(lo.w, lo.w,
                     fmaf(hi.x, hi.x, fmaf(hi.y, hi.y, fmaf(hi.z, hi.z, fmaf(hi.w, hi.w, y2p[j]))))))));
            bf[j] = cvt8(lo, hi);
        }
#pragma unroll
        for (int i = 0; i < 4; ++i)
#pragma unroll
            for (int j = 0; j < 4; ++j)
                acc[i][j] = __builtin_amdgcn_mfma_f32_16x16x32_f16(a[i], bf[j], acc[i][j], 0, 0, 0);
    }

    // y2 reduce across the 4 l4-groups (lane bits 4,5) -> col sums; wr==0 writes
#pragma unroll
    for (int j = 0; j < 4; ++j) {
        float s = y2p[j];
        s += __shfl_xor(s, 16);
        s += __shfl_xor(s, 32);
        if (wr == 0 && l4 == 0) y2s[wc * 64 + j * 16 + l15] = s;
    }
    __syncthreads();                          // y2s visible to all waves

    float yv[4];
#pragma unroll
    for (int j = 0; j < 4; ++j) yv[j] = y2s[wc * 64 + j * 16 + l15];

    // streaming zero of this block's 64 KB output slice (fire-and-forget NT
    // stores; drain hidden under the epilogue reduce + resident blocks)
    {
        f32x4* o4 = reinterpret_cast<f32x4*>(outZero) + (size_t)flat * 4096;
        const f32x4 z = (f32x4)0.0f;
#pragma unroll
        for (int it = 0; it < 16; ++it)
            __builtin_nontemporal_store(z, &o4[it * 256 + tid]);
    }

#pragma unroll
    for (int i = 0; i < 4; ++i) {
#pragma unroll
        for (int q2 = 0; q2 < 4; ++q2) {
            float v1 = INFINITY, v2 = INFINITY;
            unsigned int mi = 0u;
#pragma unroll
            for (int j = 0; j < 4; ++j) {
                const float v = fmaf(-2.0f, acc[i][j][q2], yv[j]);
                const unsigned int m = (unsigned)(col0 + wc * 64 + j * 16 + l15);
                if (v < v1) { v2 = v1; v1 = v; mi = m; }
                else        { v2 = fminf(v2, v); }
            }
#pragma unroll
            for (int off = 1; off < 16; off <<= 1) {
                float o1 = __shfl_xor(v1, off);
                float o2 = __shfl_xor(v2, off);
                unsigned int oi = __shfl_xor(mi, off);
                if (o1 < v1 || (o1 == v1 && oi < mi)) { v2 = fminf(v1, o2); v1 = o1; mi = oi; }
                else                                  { v2 = fminf(v2, fminf(o1, o2)); }
            }
            if (l15 == 0) {
                const int rl = wr * 64 + i * 16 + l4 * 4 + q2;
                rv1[wc][rl] = v1; rv2[wc][rl] = v2; ri[wc][rl] = mi;
            }
        }
    }
    __syncthreads();
    if (tid < 128) {
        float a1 = rv1[0][tid], a2 = rv2[0][tid];
        unsigned int ai = ri[0][tid];
        const float o1 = rv1[1][tid], o2 = rv2[1][tid];
        const unsigned int oi = ri[1][tid];
        if (o1 < a1 || (o1 == a1 && oi < ai)) { a2 = fminf(a1, o2); a1 = o1; ai = oi; }
        else                                  { a2 = fminf(a2, fminf(o1, o2)); }
        const size_t gr = (size_t)b * NPTS + row0 + tid;
        pv1[(size_t)bnc * NROWS + gr] = a1;
        pv2[(size_t)bnc * NROWS + gr] = a2;
        pidx[(size_t)bnc * NROWS + gr] = ai;
    }
}

// ---- fused resolve + candidate-window fp64 recheck (R10/R11-proven) -----------
__global__ __launch_bounds__(256) void finalize_kernel(
    const float* __restrict__ f0, const float* __restrict__ f1,
    const float* __restrict__ pv1, const float* __restrict__ pv2,
    const unsigned int* __restrict__ pidx,
    float* __restrict__ out)
{
    __shared__ float xrow[4][DDIM];
    __shared__ unsigned int cand[4][WCAP];
    __shared__ int ncand[4];
    __shared__ float s_best[64];
    __shared__ unsigned char s_flag[64];
    __shared__ int s_nflag;

    const int tid = threadIdx.x;
    const int gr0 = blockIdx.x * 64;

    if (tid == 0) s_nflag = 0;
    __syncthreads();

    // ---- phase 1: resolve (4 threads per row, each scans 16 tiles) ----
    {
        const int r  = tid >> 2;       // 0..63 local row
        const int q  = tid & 3;
        const int gr = gr0 + r;
        float a1 = INFINITY, a2 = INFINITY;
        unsigned int ai = 0u;
#pragma unroll 4
        for (int c = 0; c < 16; ++c) {
            const int cs = q * 16 + c;
            const size_t base = (size_t)cs * NROWS + gr;
            const float o1 = pv1[base];
            const float o2 = pv2[base];
            const unsigned int oi = pidx[base];
            if (o1 < a1 || (o1 == a1 && oi < ai)) { a2 = fminf(a1, o2); a1 = o1; ai = oi; }
            else                                  { a2 = fminf(a2, fminf(o1, o2)); }
        }
#pragma unroll
        for (int off = 1; off < 4; off <<= 1) {
            const float o1 = __shfl_xor(a1, off);
            const float o2 = __shfl_xor(a2, off);
            const unsigned int oi = __shfl_xor(ai, off);
            if (o1 < a1 || (o1 == a1 && oi < ai)) { a2 = fminf(a1, o2); a1 = o1; ai = oi; }
            else                                  { a2 = fminf(a2, fminf(o1, o2)); }
        }
        if (q == 0) {
            if (a2 - a1 < EPSGAP) {
                const int p = atomicAdd(&s_nflag, 1);
                s_flag[p] = (unsigned char)r;
                s_best[r] = a1;
            } else {
                out[(size_t)gr * NPTS + ai] = 1.0f;
                out[(size_t)BATCH * NPTS * NPTS + gr] = (float)ai;
            }
        }
    }
    __syncthreads();

    // ---- phase 2: wave-per-flagged-row fp64 recheck ----
    const int nf   = s_nflag;
    const int w    = tid >> 6;
    const int lane = tid & 63;

    for (int li = w; li < nf; li += 4) {
        const int rr = (int)s_flag[li];
        const int gr = gr0 + rr;
        const int b = gr >> 13, n = gr & (NPTS - 1);
        const float W = s_best[rr] + EPSGAP;

        if (lane == 0) ncand[w] = 0;
        const float* xp = f0 + ((size_t)b * NPTS + n) * DDIM;
        xrow[w][lane]      = xp[lane];
        xrow[w][lane + 64] = xp[lane + 64];

        // screen: lane == tile index
        {
            const size_t base = (size_t)lane * NROWS + gr;
            const float t1 = pv1[base];
            if (t1 <= W) {
                if (pv2[base] <= W) {
                    int p = atomicAdd(&ncand[w], 128);
                    if (p + 128 <= WCAP)
                        for (int c = 0; c < 128; ++c) cand[w][p + c] = (unsigned)(lane * 128 + c);
                } else {
                    int p = atomicAdd(&ncand[w], 1);
                    if (p < WCAP) cand[w][p] = pidx[base];
                }
            }
        }
        asm volatile("s_waitcnt lgkmcnt(0)" ::: "memory");  // wave-local LDS drain

        const int nc = ncand[w];
        double bv = 1e300;
        unsigned int bi = 0xFFFFFFFFu;
        const float4* xpv = reinterpret_cast<const float4*>(xrow[w]);
        if (nc <= WCAP) {
            for (int c = lane; c < nc; c += 64) {
                const unsigned int m = cand[w][c];
                const float4* ypv = reinterpret_cast<const float4*>(f1 + ((size_t)b * NPTS + m) * DDIM);
                double s0 = 0.0, s1 = 0.0, s2 = 0.0, s3 = 0.0;
#pragma unroll 8
                for (int k4 = 0; k4 < DDIM / 4; ++k4) {
                    const float4 y = ypv[k4];
                    const float4 x = xpv[k4];
                    s0 = fma((double)y.x, (double)y.x - 2.0 * (double)x.x, s0);
                    s1 = fma((double)y.y, (double)y.y - 2.0 * (double)x.y, s1);
                    s2 = fma((double)y.z, (double)y.z - 2.0 * (double)x.z, s2);
                    s3 = fma((double)y.w, (double)y.w - 2.0 * (double)x.w, s3);
                }
                const double v = (s0 + s1) + (s2 + s3);
                if (v < bv || (v == bv && m < bi)) { bv = v; bi = m; }
            }
        } else {
            for (int m = lane; m < NPTS; m += 64) {
                const float4* ypv = reinterpret_cast<const float4*>(f1 + ((size_t)b * NPTS + m) * DDIM);
                double s0 = 0.0, s1 = 0.0, s2 = 0.0, s3 = 0.0;
#pragma unroll 4
                for (int k4 = 0; k4 < DDIM / 4; ++k4) {
                    const float4 y = ypv[k4];
                    const float4 x = xpv[k4];
                    s0 = fma((double)y.x, (double)y.x - 2.0 * (double)x.x, s0);
                    s1 = fma((double)y.y, (double)y.y - 2.0 * (double)x.y, s1);
                    s2 = fma((double)y.z, (double)y.z - 2.0 * (double)x.z, s2);
                    s3 = fma((double)y.w, (double)y.w - 2.0 * (double)x.w, s3);
                }
                const double v = (s0 + s1) + (s2 + s3);
                if (v < bv || (v == bv && (unsigned)m < bi)) { bv = v; bi = (unsigned)m; }
            }
        }
#pragma unroll
        for (int off = 1; off < 64; off <<= 1) {
            const double ov = __shfl_xor(bv, off);
            const unsigned int oi = __shfl_xor(bi, off);
            if (ov < bv || (ov == bv && oi < bi)) { bv = ov; bi = oi; }
        }
        if (lane == 0) {
            out[(size_t)gr * NPTS + bi] = 1.0f;
            out[(size_t)BATCH * NPTS * NPTS + gr] = (float)bi;
        }
        asm volatile("s_waitcnt lgkmcnt(0)" ::: "memory");  // before LDS reuse next iter
    }
}

extern "C" void kernel_launch(void* const* d_in, const int* in_sizes, int n_in,
                              void* d_out, int out_size, void* d_ws, size_t ws_size,
                              hipStream_t stream)
{
    const float* f0 = (const float*)d_in[0];
    const float* f1 = (const float*)d_in[1];
    float* out = (float*)d_out;

    // ws layout (bytes): pv1 4.19M | pv2 4.19M | pidx 4.19M   (~12.6 MB)
    char* wsb = (char*)d_ws;
    float* pv1           = (float*)wsb;                           wsb += (size_t)NCOLT * NROWS * 4;
    float* pv2           = (float*)wsb;                           wsb += (size_t)NCOLT * NROWS * 4;
    unsigned int* pidx   = (unsigned int*)wsb;

    gemm_mfma<<<NPTS / 128 * NPTS / 128 * BATCH, 256, 0, stream>>>(f0, f1, pv1, pv2, pidx, out);
    finalize_kernel<<<NROWS / 64, 256, 0, stream>>>(f0, f1, pv1, pv2, pidx, out);
}

// Round 14
// 193.178 us; speedup vs baseline: 1.1485x; 1.1485x over previous
//
#include <hip/hip_runtime.h>
#include <hip/hip_fp16.h>
#include <cstdint>
#include <cstddef>

#define NPTS 8192
#define DDIM 128
#define BATCH 2
#define NROWS (BATCH * NPTS)
#define EPSGAP 1.0f   // certified: 2*max dist err (f16, 2^-11 u) <= ~0.4 < 1.0 (R7/R8/R10/R11 validated)
#define NCOLT 64      // 8192 / 128 column tiles (partials per row)
#define WCAP 512      // per-wave candidate capacity in finalize phase 2

typedef __attribute__((ext_vector_type(8))) _Float16 half8v;
typedef __attribute__((ext_vector_type(4))) float f32x4;

typedef __attribute__((address_space(3))) unsigned int as3_uint;
typedef const __attribute__((address_space(1))) unsigned int as1_uint;

// ---- fused split: fp32 -> f16 rows for BOTH inputs; y2 for f1 -----------------
// (R8/R11-proven. R9/R13 both showed fusing this into gemm loses: f16 split pays
// the 128 MB fp32 read once; gemm then stages 4x fewer bytes via global_load_lds.)
__global__ void split_kernel(const float* __restrict__ f0, const float* __restrict__ f1,
                             unsigned short* __restrict__ Aext, unsigned short* __restrict__ Bext,
                             float* __restrict__ y2) {
    const unsigned half = gridDim.x >> 1;          // 2048
    const bool isB = blockIdx.x >= half;
    const float* src = isB ? f1 : f0;
    unsigned short* dst = isB ? Bext : Aext;
    size_t t = (size_t)(blockIdx.x - (isB ? half : 0)) * 256 + threadIdx.x;  // one per 4 elems
    size_t row = t >> 5;
    int kc = (int)(t & 31) * 4;
    float4 v = reinterpret_cast<const float4*>(src)[t];
    ushort4 h;
    h.x = __half_as_ushort(__float2half(v.x));
    h.y = __half_as_ushort(__float2half(v.y));
    h.z = __half_as_ushort(__float2half(v.z));
    h.w = __half_as_ushort(__float2half(v.w));
    *reinterpret_cast<ushort4*>(&dst[row * 128 + kc]) = h;

    if (isB) {
        // 32 consecutive threads own one row; reduce sum of squares (fp32)
        float s = fmaf(v.x, v.x, fmaf(v.y, v.y, fmaf(v.z, v.z, v.w * v.w)));
#pragma unroll
        for (int off = 16; off >= 1; off >>= 1) s += __shfl_xor(s, off);
        if ((t & 31) == 0) y2[row] = s;
    }
}

// ---- MFMA GEMM (f16, K=128) + top-2 argmin epilogue + FULL output zeroing -----
// R11-proven: global_load_lds staging (inverse-swizzled source), 1-D grid 8192
// XCD-swizzled, 64 KB zero slice per block issued post-MFMA (drain fully hidden
// under the epilogue reduce + resident blocks — validated R8/R10/R11).
__global__ __launch_bounds__(256) void gemm_mfma(
    const unsigned short* __restrict__ Aext,  // [B][N][128] f16 bits
    const unsigned short* __restrict__ Bext,
    const float* __restrict__ y2g,
    float* __restrict__ pv1, float* __restrict__ pv2, unsigned int* __restrict__ pidx,
    float* __restrict__ outZero)
{
    __shared__ __align__(16) short As[128 * 64];
    __shared__ __align__(16) short Bs[128 * 64];
    __shared__ float rv1[2][128];
    __shared__ float rv2[2][128];
    __shared__ unsigned int ri[2][128];

    const unsigned flat = blockIdx.x;                         // 0..8191
    const unsigned wg   = (flat & 7u) * 1024u + (flat >> 3);  // bijective XCD chunking
    const int bm  = wg & 63;
    const int bnc = (int)((wg >> 6) & 63);
    const int b   = (int)(wg >> 12);

    const int tid  = threadIdx.x;
    const int lane = tid & 63;
    const int wid  = tid >> 6;
    const int wr   = wid >> 1, wc = wid & 1;
    const int l15  = lane & 15, l4 = lane >> 4;
    const int row0 = bm * 128, col0 = bnc * 128;

    const unsigned short* Abase = Aext + ((size_t)b * NPTS + row0) * 128;
    const unsigned short* Bbase = Bext + ((size_t)b * NPTS + col0) * 128;

    f32x4 acc[4][4];
#pragma unroll
    for (int i = 0; i < 4; ++i)
#pragma unroll
        for (int j = 0; j < 4; ++j) acc[i][j] = (f32x4)0.0f;

#pragma unroll
    for (int kk = 0; kk < 2; ++kk) {          // K halves: cols [0,64) and [64,128)
        __syncthreads();
        {
            const int ko = kk * 64;
#pragma unroll
            for (int it = 0; it < 4; ++it) {
                int flat2 = it * 256 + tid;   // 16B-chunk id 0..1023 (128 rows x 8 chunks)
                int r = flat2 >> 3, kc = flat2 & 7;
                int kcs = kc ^ (r & 7);       // inverse-swizzled source chunk
                const unsigned short* ga = Abase + (size_t)r * 128 + ko + kcs * 8;
                const unsigned short* gb = Bbase + (size_t)r * 128 + ko + kcs * 8;
                __builtin_amdgcn_global_load_lds((as1_uint*)ga, (as3_uint*)&As[flat2 * 8], 16, 0, 0);
                __builtin_amdgcn_global_load_lds((as1_uint*)gb, (as3_uint*)&Bs[flat2 * 8], 16, 0, 0);
            }
        }
        __syncthreads();
#pragma unroll
        for (int ks = 0; ks < 2; ++ks) {
            half8v a[4], bf[4];
#pragma unroll
            for (int i = 0; i < 4; ++i) {
                int ra = wr * 64 + i * 16 + l15;
                int ch = ks * 4 + l4;
                a[i] = *reinterpret_cast<const half8v*>(&As[ra * 64 + ((ch ^ (ra & 7)) << 3)]);
            }
#pragma unroll
            for (int j = 0; j < 4; ++j) {
                int rb = wc * 64 + j * 16 + l15;
                int ch = ks * 4 + l4;
                bf[j] = *reinterpret_cast<const half8v*>(&Bs[rb * 64 + ((ch ^ (rb & 7)) << 3)]);
            }
#pragma unroll
            for (int i = 0; i < 4; ++i)
#pragma unroll
                for (int j = 0; j < 4; ++j)
                    acc[i][j] = __builtin_amdgcn_mfma_f32_16x16x32_f16(a[i], bf[j], acc[i][j], 0, 0, 0);
        }
    }

    // hoist y2 loads BEFORE the zero stores (their vmcnt wait excludes the stores)
    const float* y2b = y2g + b * NPTS;
    float yv[4];
#pragma unroll
    for (int j = 0; j < 4; ++j) yv[j] = y2b[col0 + wc * 64 + j * 16 + l15];

    // streaming zero of this block's 64 KB output slice — issued early so the
    // epilogue's shuffle/LDS reduce hides the drain
    {
        f32x4* o4 = reinterpret_cast<f32x4*>(outZero) + (size_t)wg * 4096;
        const f32x4 z = (f32x4)0.0f;
#pragma unroll
        for (int it = 0; it < 16; ++it)
            __builtin_nontemporal_store(z, &o4[it * 256 + tid]);
    }

#pragma unroll
    for (int i = 0; i < 4; ++i) {
#pragma unroll
        for (int q = 0; q < 4; ++q) {
            float v1 = INFINITY, v2 = INFINITY;
            unsigned int mi = 0u;
#pragma unroll
            for (int j = 0; j < 4; ++j) {
                const float v = fmaf(-2.0f, acc[i][j][q], yv[j]);
                const unsigned int m = (unsigned)(col0 + wc * 64 + j * 16 + l15);
                if (v < v1) { v2 = v1; v1 = v; mi = m; }
                else        { v2 = fminf(v2, v); }
            }
#pragma unroll
            for (int off = 1; off < 16; off <<= 1) {
                float o1 = __shfl_xor(v1, off);
                float o2 = __shfl_xor(v2, off);
                unsigned int oi = __shfl_xor(mi, off);
                if (o1 < v1 || (o1 == v1 && oi < mi)) { v2 = fminf(v1, o2); v1 = o1; mi = oi; }
                else                                  { v2 = fminf(v2, fminf(o1, o2)); }
            }
            if (l15 == 0) {
                const int rl = wr * 64 + i * 16 + l4 * 4 + q;
                rv1[wc][rl] = v1; rv2[wc][rl] = v2; ri[wc][rl] = mi;
            }
        }
    }
    __syncthreads();
    if (tid < 128) {
        float a1 = rv1[0][tid], a2 = rv2[0][tid];
        unsigned int ai = ri[0][tid];
        const float o1 = rv1[1][tid], o2 = rv2[1][tid];
        const unsigned int oi = ri[1][tid];
        if (o1 < a1 || (o1 == a1 && oi < ai)) { a2 = fminf(a1, o2); a1 = o1; ai = oi; }
        else                                  { a2 = fminf(a2, fminf(o1, o2)); }
        const size_t gr = (size_t)b * NPTS + row0 + tid;
        pv1[(size_t)bnc * NROWS + gr] = a1;
        pv2[(size_t)bnc * NROWS + gr] = a2;
        pidx[(size_t)bnc * NROWS + gr] = ai;
    }
}

// ---- fused resolve + candidate-window fp64 recheck (R10/R11-proven) -----------
// 256 blocks x 64 rows. Phase 1: 4 threads/row shuffle-merge the 64 tile
// partials; unflagged rows write output immediately; flagged rows go to a
// block-local list. Phase 2: the block's 4 waves recheck flagged rows.
__global__ __launch_bounds__(256) void finalize_kernel(
    const float* __restrict__ f0, const float* __restrict__ f1,
    const float* __restrict__ pv1, const float* __restrict__ pv2,
    const unsigned int* __restrict__ pidx,
    float* __restrict__ out)
{
    __shared__ float xrow[4][DDIM];
    __shared__ unsigned int cand[4][WCAP];
    __shared__ int ncand[4];
    __shared__ float s_best[64];
    __shared__ unsigned char s_flag[64];
    __shared__ int s_nflag;

    const int tid = threadIdx.x;
    const int gr0 = blockIdx.x * 64;

    if (tid == 0) s_nflag = 0;
    __syncthreads();

    // ---- phase 1: resolve (4 threads per row, each scans 16 tiles) ----
    {
        const int r  = tid >> 2;       // 0..63 local row
        const int q  = tid & 3;
        const int gr = gr0 + r;
        float a1 = INFINITY, a2 = INFINITY;
        unsigned int ai = 0u;
#pragma unroll 4
        for (int c = 0; c < 16; ++c) {
            const int cs = q * 16 + c;
            const size_t base = (size_t)cs * NROWS + gr;
            const float o1 = pv1[base];
            const float o2 = pv2[base];
            const unsigned int oi = pidx[base];
            if (o1 < a1 || (o1 == a1 && oi < ai)) { a2 = fminf(a1, o2); a1 = o1; ai = oi; }
            else                                  { a2 = fminf(a2, fminf(o1, o2)); }
        }
        // merge across the 4 lanes of this row (4-lane groups never straddle a wave)
#pragma unroll
        for (int off = 1; off < 4; off <<= 1) {
            const float o1 = __shfl_xor(a1, off);
            const float o2 = __shfl_xor(a2, off);
            const unsigned int oi = __shfl_xor(ai, off);
            if (o1 < a1 || (o1 == a1 && oi < ai)) { a2 = fminf(a1, o2); a1 = o1; ai = oi; }
            else                                  { a2 = fminf(a2, fminf(o1, o2)); }
        }
        if (q == 0) {
            if (a2 - a1 < EPSGAP) {
                const int p = atomicAdd(&s_nflag, 1);
                s_flag[p] = (unsigned char)r;
                s_best[r] = a1;
            } else {
                out[(size_t)gr * NPTS + ai] = 1.0f;
                out[(size_t)BATCH * NPTS * NPTS + gr] = (float)ai;
            }
        }
    }
    __syncthreads();

    // ---- phase 2: wave-per-flagged-row fp64 recheck ----
    const int nf   = s_nflag;
    const int w    = tid >> 6;
    const int lane = tid & 63;

    for (int li = w; li < nf; li += 4) {
        const int rr = (int)s_flag[li];
        const int gr = gr0 + rr;
        const int b = gr >> 13, n = gr & (NPTS - 1);
        const float W = s_best[rr] + EPSGAP;

        if (lane == 0) ncand[w] = 0;
        const float* xp = f0 + ((size_t)b * NPTS + n) * DDIM;
        xrow[w][lane]      = xp[lane];
        xrow[w][lane + 64] = xp[lane + 64];

        // screen: lane == tile index
        {
            const size_t base = (size_t)lane * NROWS + gr;
            const float t1 = pv1[base];
            if (t1 <= W) {
                if (pv2[base] <= W) {
                    int p = atomicAdd(&ncand[w], 128);
                    if (p + 128 <= WCAP)
                        for (int c = 0; c < 128; ++c) cand[w][p + c] = (unsigned)(lane * 128 + c);
                } else {
                    int p = atomicAdd(&ncand[w], 1);
                    if (p < WCAP) cand[w][p] = pidx[base];
                }
            }
        }
        asm volatile("s_waitcnt lgkmcnt(0)" ::: "memory");  // wave-local LDS drain

        const int nc = ncand[w];
        double bv = 1e300;
        unsigned int bi = 0xFFFFFFFFu;
        const float4* xpv = reinterpret_cast<const float4*>(xrow[w]);
        if (nc <= WCAP) {
            for (int c = lane; c < nc; c += 64) {
                const unsigned int m = cand[w][c];
                const float4* ypv = reinterpret_cast<const float4*>(f1 + ((size_t)b * NPTS + m) * DDIM);
                double s0 = 0.0, s1 = 0.0, s2 = 0.0, s3 = 0.0;
#pragma unroll 8
                for (int k4 = 0; k4 < DDIM / 4; ++k4) {
                    const float4 y = ypv[k4];
                    const float4 x = xpv[k4];
                    s0 = fma((double)y.x, (double)y.x - 2.0 * (double)x.x, s0);
                    s1 = fma((double)y.y, (double)y.y - 2.0 * (double)x.y, s1);
                    s2 = fma((double)y.z, (double)y.z - 2.0 * (double)x.z, s2);
                    s3 = fma((double)y.w, (double)y.w - 2.0 * (double)x.w, s3);
                }
                const double v = (s0 + s1) + (s2 + s3);
                if (v < bv || (v == bv && m < bi)) { bv = v; bi = m; }
            }
        } else {
            for (int m = lane; m < NPTS; m += 64) {
                const float4* ypv = reinterpret_cast<const float4*>(f1 + ((size_t)b * NPTS + m) * DDIM);
                double s0 = 0.0, s1 = 0.0, s2 = 0.0, s3 = 0.0;
#pragma unroll 4
                for (int k4 = 0; k4 < DDIM / 4; ++k4) {
                    const float4 y = ypv[k4];
                    const float4 x = xpv[k4];
                    s0 = fma((double)y.x, (double)y.x - 2.0 * (double)x.x, s0);
                    s1 = fma((double)y.y, (double)y.y - 2.0 * (double)x.y, s1);
                    s2 = fma((double)y.z, (double)y.z - 2.0 * (double)x.z, s2);
                    s3 = fma((double)y.w, (double)y.w - 2.0 * (double)x.w, s3);
                }
                const double v = (s0 + s1) + (s2 + s3);
                if (v < bv || (v == bv && (unsigned)m < bi)) { bv = v; bi = (unsigned)m; }
            }
        }
        // wave argmin reduce (exact doubles; first-occurrence tie-break)
#pragma unroll
        for (int off = 1; off < 64; off <<= 1) {
            const double ov = __shfl_xor(bv, off);
            const unsigned int oi = __shfl_xor(bi, off);
            if (ov < bv || (ov == bv && oi < bi)) { bv = ov; bi = oi; }
        }
        if (lane == 0) {
            out[(size_t)gr * NPTS + bi] = 1.0f;
            out[(size_t)BATCH * NPTS * NPTS + gr] = (float)bi;
        }
        asm volatile("s_waitcnt lgkmcnt(0)" ::: "memory");  // before LDS reuse next iter
    }
}

extern "C" void kernel_launch(void* const* d_in, const int* in_sizes, int n_in,
                              void* d_out, int out_size, void* d_ws, size_t ws_size,
                              hipStream_t stream)
{
    const float* f0 = (const float*)d_in[0];
    const float* f1 = (const float*)d_in[1];
    float* out = (float*)d_out;

    // ws layout (bytes): Aext 4.19M | Bext 4.19M | y2 64K | pv1 4.19M | pv2 4.19M
    //                    | pidx 4.19M   (~21 MB)
    char* wsb = (char*)d_ws;
    unsigned short* Aext = (unsigned short*)wsb;                  wsb += (size_t)BATCH * NPTS * 128 * 2;
    unsigned short* Bext = (unsigned short*)wsb;                  wsb += (size_t)BATCH * NPTS * 128 * 2;
    float* y2            = (float*)wsb;                           wsb += (size_t)NROWS * 4;
    float* pv1           = (float*)wsb;                           wsb += (size_t)NCOLT * NROWS * 4;
    float* pv2           = (float*)wsb;                           wsb += (size_t)NCOLT * NROWS * 4;
    unsigned int* pidx   = (unsigned int*)wsb;

    split_kernel<<<2 * (BATCH * NPTS * 32) / 256, 256, 0, stream>>>(f0, f1, Aext, Bext, y2);
    gemm_mfma<<<NPTS / 128 * NPTS / 128 * BATCH, 256, 0, stream>>>(Aext, Bext, y2, pv1, pv2, pidx, out);
    finalize_kernel<<<NROWS / 64, 256, 0, stream>>>(f0, f1, pv1, pv2, pidx, out);
}